// Round 1
// baseline (88.692 us; speedup 1.0000x reference)
//
#include <hip/hip_runtime.h>

// SSF_Extractor: out = x * resize_bilinear_ac(local_unbiased_var_5x5(x), H, W)
// x: (8, 64, 256, 256) fp32. Fused single kernel, one 32x32 output tile per block.

namespace {

constexpr int H = 256, W = 256;
constexpr int VH = 252, VW = 252;   // var map dims (VALID 5x5)
constexpr int OT = 32;              // output tile
constexpr int XT = 37;              // staged x tile (33 var rows + 4)
constexpr int VT = 33;              // var rows/cols needed per tile

#define SCALE_F (251.0f / 255.0f)   // align_corners scale (h-1)/(H-1)

__global__ __launch_bounds__(256, 2) void ssf_fused(const float* __restrict__ x,
                                                    float* __restrict__ out) {
  __shared__ float sx[XT][XT];        // staged x window
  __shared__ float cs[VT][XT];        // 5-row column sums of x
  __shared__ float css[VT][XT];       // 5-row column sums of x^2
  __shared__ float svar[VT][VT + 1];  // variance tile (padded)
  __shared__ int   iy0[OT];
  __shared__ float fwy[OT];
  __shared__ int   ix0[OT];
  __shared__ float fwx[OT];

  const int tid = threadIdx.x;
  const int img = blockIdx.z;
  const int by = blockIdx.y * OT;
  const int bx = blockIdx.x * OT;

  const float* xi = x + (size_t)img * (H * W);
  float* oi = out + (size_t)img * (H * W);

  const int vy0 = (int)floorf(by * SCALE_F);
  const int vx0 = (int)floorf(bx * SCALE_F);

  // Precompute bilinear coords/weights for this tile's 32 rows and 32 cols.
  if (tid < OT) {
    float ys = (float)(by + tid) * SCALE_F;
    int y0 = (int)floorf(ys);
    iy0[tid] = y0;
    fwy[tid] = ys - (float)y0;
  } else if (tid < 2 * OT) {
    int t = tid - OT;
    float xs = (float)(bx + t) * SCALE_F;
    int x0 = (int)floorf(xs);
    ix0[t] = x0;
    fwx[t] = xs - (float)x0;
  }

  // Stage x window (clamped at image edge; clamped values are finite and
  // only feed var entries that are never read back).
  for (int idx = tid; idx < XT * XT; idx += 256) {
    int r = idx / XT, c = idx - r * XT;
    int gy = vy0 + r; gy = gy > H - 1 ? H - 1 : gy;
    int gx = vx0 + c; gx = gx > W - 1 ? W - 1 : gx;
    sx[r][c] = xi[gy * W + gx];
  }
  __syncthreads();

  // Pass B: vertical 5-row sums (and sums of squares), per column.
  // Work item = (column c, 5-row segment). Static 9-value register window.
  for (int item = tid; item < XT * 7; item += 256) {
    int c = item % XT;
    int seg = item / XT;
    int r0 = seg * 5;
    float v[9];
#pragma unroll
    for (int d = 0; d < 9; ++d) {
      int r = r0 + d; r = r > XT - 1 ? XT - 1 : r;
      v[d] = sx[r][c];
    }
#pragma unroll
    for (int d = 0; d < 5; ++d) {
      int r = r0 + d;
      if (r < VT) {
        float s  = v[d] + v[d + 1] + v[d + 2] + v[d + 3] + v[d + 4];
        float s2 = v[d] * v[d] + v[d + 1] * v[d + 1] + v[d + 2] * v[d + 2] +
                   v[d + 3] * v[d + 3] + v[d + 4] * v[d + 4];
        cs[r][c]  = s;
        css[r][c] = s2;
      }
    }
  }
  __syncthreads();

  // Pass C: horizontal 5-col sums -> unbiased variance.
  for (int item = tid; item < VT * 7; item += 256) {
    int r = item % VT;
    int seg = item / VT;
    int c0 = seg * 5;
    float a[9], b[9];
#pragma unroll
    for (int d = 0; d < 9; ++d) {
      int c = c0 + d; c = c > XT - 1 ? XT - 1 : c;
      a[d] = cs[r][c];
      b[d] = css[r][c];
    }
#pragma unroll
    for (int d = 0; d < 5; ++d) {
      int c = c0 + d;
      if (c < VT) {
        float s  = a[d] + a[d + 1] + a[d + 2] + a[d + 3] + a[d + 4];
        float s2 = b[d] + b[d + 1] + b[d + 2] + b[d + 3] + b[d + 4];
        svar[r][c] = (s2 - s * s * (1.0f / 25.0f)) * (1.0f / 24.0f);
      }
    }
  }
  __syncthreads();

  // Pass D: bilinear upsample from svar + multiply by x, 4 pixels/thread.
  {
    int col = tid & 31;
    int row0 = tid >> 5;  // 0..7
    int gx0 = ix0[col];
    int X0 = gx0 - vx0;
    int X1 = (gx0 + 1 < VW ? gx0 + 1 : VW - 1) - vx0;
    float wx = fwx[col];
    int gxx = bx + col;
#pragma unroll
    for (int k = 0; k < 4; ++k) {
      int r = row0 + 8 * k;
      int y = by + r;
      int gy0 = iy0[r];
      int Y0 = gy0 - vy0;
      int Y1 = (gy0 + 1 < VH ? gy0 + 1 : VH - 1) - vy0;
      float wy = fwy[r];
      float v00 = svar[Y0][X0], v01 = svar[Y0][X1];
      float v10 = svar[Y1][X0], v11 = svar[Y1][X1];
      // Match reference order: rows first (wy), then cols (wx).
      float left  = v00 * (1.0f - wy) + v10 * wy;
      float right = v01 * (1.0f - wy) + v11 * wy;
      float val = left * (1.0f - wx) + right * wx;
      float xv = xi[y * W + gxx];
      oi[y * W + gxx] = xv * val;
    }
  }
}

}  // namespace

extern "C" void kernel_launch(void* const* d_in, const int* in_sizes, int n_in,
                              void* d_out, int out_size, void* d_ws, size_t ws_size,
                              hipStream_t stream) {
  const float* x = (const float*)d_in[0];
  float* out = (float*)d_out;
  dim3 grid(W / OT, H / OT, 8 * 64);  // 8x8 tiles x 512 images
  ssf_fused<<<grid, dim3(256), 0, stream>>>(x, out);
}